// Round 12
// baseline (842.166 us; speedup 1.0000x reference)
//
#include <hip/hip_runtime.h>
#include <hip/hip_bf16.h>
#include <stdint.h>

#define S_TOK 8192
#define H_DIM 2048
#define I_DIM 2048
#define E_NUM 8

typedef __attribute__((ext_vector_type(4))) float f32x4;
typedef __attribute__((ext_vector_type(16))) float f32x16;
typedef __attribute__((ext_vector_type(8))) short bf16x8;
typedef __attribute__((ext_vector_type(8))) unsigned short u16x8;

#define MFMA32(a, b, c) __builtin_amdgcn_mfma_f32_32x32x16_bf16((a), (b), (c), 0, 0, 0)

// f32 -> bf16 RNE
__device__ __forceinline__ unsigned short f2bf(float f) {
    unsigned int u = __float_as_uint(f);
    unsigned int r = (u + 0x7FFFu + ((u >> 16) & 1u)) >> 16;
    return (unsigned short)r;
}
__device__ __forceinline__ float bf2f(unsigned short u) {
    return __uint_as_float((unsigned int)u << 16);
}

__device__ __forceinline__ void cvt8(const float* __restrict__ s, unsigned short* __restrict__ d) {
    float4 v0 = *(const float4*)s;
    float4 v1 = *(const float4*)(s + 4);
    u16x8 o;
    o[0] = f2bf(v0.x); o[1] = f2bf(v0.y); o[2] = f2bf(v0.z); o[3] = f2bf(v0.w);
    o[4] = f2bf(v1.x); o[5] = f2bf(v1.y); o[6] = f2bf(v1.z); o[7] = f2bf(v1.w);
    *(u16x8*)d = o;
}

// async global->LDS, 16B per lane. LDS dest is wave-uniform base + lane*16.
__device__ __forceinline__ void async_copy16(void* lds, const void* g) {
    __builtin_amdgcn_global_load_lds(
        (const __attribute__((address_space(1))) void*)(uintptr_t)g,
        (__attribute__((address_space(3))) void*)(uintptr_t)lds,
        16, 0, 0);
}

// XCD-aware block swizzle (nwg % 8 == 0 for all our grids)
__device__ __forceinline__ int xcd_swizzle(int bid, int nwg) {
    int cpx = nwg >> 3;
    return (bid & 7) * cpx + (bid >> 3);
}

// ---------------- flat f32 -> bf16 conversion (fallback path) ----------------
__global__ void cvt_kernel(const float* __restrict__ src, unsigned short* __restrict__ dst, long n) {
    long i0 = ((long)blockIdx.x * blockDim.x + threadIdx.x) * 8;
    long stride = (long)gridDim.x * blockDim.x * 8;
    for (long i = i0; i < n; i += stride) cvt8(src + i, dst + i);
}

// ---------------- w1 half conversion ----------------
template<int HALF>
__device__ __forceinline__ void cvt_w1_half_body(const float* __restrict__ src,
                                                 unsigned short* __restrict__ dst,
                                                 long i0, long stride) {
    const long CH = 1L << 21;                 // 1024*2048
    const long TOT = (long)E_NUM * 2 * CH;    // 16.8M
    for (long j = i0; j < TOT; j += stride) {
        long e = j >> 22;
        long piece = (j >> 21) & 1;
        long off = j & (CH - 1);
        long g = (e << 23) + ((piece * 2 + HALF) << 21) + off;
        cvt8(src + g, dst + g);
    }
}

// ---------------- router: logits (f32 exact), top-2 choice, hs->bf16 ----------------
__global__ void router_kernel(const float* __restrict__ hs, const float* __restrict__ wg,
                              float* __restrict__ logits,
                              unsigned int* __restrict__ tchoice, float* __restrict__ twgt,
                              unsigned short* __restrict__ hsb,
                              const float* __restrict__ w1src, unsigned short* __restrict__ w1dst,
                              int cvt_blks) {
    if ((int)blockIdx.x >= S_TOK) {
        long i0 = ((long)((int)blockIdx.x - S_TOK) * blockDim.x + threadIdx.x) * 8;
        long stride = (long)cvt_blks * blockDim.x * 8;
        cvt_w1_half_body<0>(w1src, w1dst, i0, stride);
        return;
    }
    int t = blockIdx.x;
    int tid = threadIdx.x;
    const float* hrow = hs + (size_t)t * H_DIM;
    float4 h0 = *(const float4*)(hrow + tid * 8);
    float4 h1 = *(const float4*)(hrow + tid * 8 + 4);
    u16x8 o;
    o[0] = f2bf(h0.x); o[1] = f2bf(h0.y); o[2] = f2bf(h0.z); o[3] = f2bf(h0.w);
    o[4] = f2bf(h1.x); o[5] = f2bf(h1.y); o[6] = f2bf(h1.z); o[7] = f2bf(h1.w);
    *(u16x8*)(hsb + (size_t)t * H_DIM + tid * 8) = o;

    float p[E_NUM];
#pragma unroll
    for (int e = 0; e < E_NUM; ++e) {
        const float* w = wg + (size_t)e * H_DIM + tid * 8;
        float4 w0 = *(const float4*)(w);
        float4 w1v = *(const float4*)(w + 4);
        p[e] = h0.x * w0.x + h0.y * w0.y + h0.z * w0.z + h0.w * w0.w +
               h1.x * w1v.x + h1.y * w1v.y + h1.z * w1v.z + h1.w * w1v.w;
    }
#pragma unroll
    for (int e = 0; e < E_NUM; ++e)
#pragma unroll
        for (int d = 32; d > 0; d >>= 1) p[e] += __shfl_xor(p[e], d, 64);

    __shared__ float red[4][E_NUM];
    int wave = tid >> 6, lane = tid & 63;
    if (lane == 0) {
#pragma unroll
        for (int e = 0; e < E_NUM; ++e) red[wave][e] = p[e];
    }
    __syncthreads();
    if (tid == 0) {
        float l[E_NUM];
#pragma unroll
        for (int e = 0; e < E_NUM; ++e) l[e] = red[0][e] + red[1][e] + red[2][e] + red[3][e];
#pragma unroll
        for (int e = 0; e < E_NUM; ++e) logits[(size_t)t * E_NUM + e] = l[e];
        int i1 = 0;
#pragma unroll
        for (int e = 1; e < E_NUM; ++e) if (l[e] > l[i1]) i1 = e;
        int i2 = (i1 == 0) ? 1 : 0;
#pragma unroll
        for (int e = 0; e < E_NUM; ++e) if (e != i1 && l[e] > l[i2]) i2 = e;
        float b = __expf(l[i2] - l[i1]);
        tchoice[t] = (unsigned)i1 | ((unsigned)i2 << 4);
        twgt[t] = 1.0f / (1.0f + b);
    }
}

// ---------------- scan: deterministic slot assignment (token order) ----------------
__global__ __launch_bounds__(1024) void scan_kernel(
    const unsigned int* __restrict__ tchoice, const float* __restrict__ twgt,
    int* __restrict__ cnt, int* __restrict__ off,
    int* __restrict__ tok_of, float* __restrict__ wgt_of,
    unsigned int* __restrict__ slot_of) {
    __shared__ int lcnt[E_NUM][1024];
    __shared__ int tot[E_NUM];
    int tid = threadIdx.x;
    unsigned int ch[8];
    int c[E_NUM];
#pragma unroll
    for (int e = 0; e < E_NUM; ++e) c[e] = 0;
#pragma unroll
    for (int k = 0; k < 8; ++k) {
        ch[k] = tchoice[tid * 8 + k];
        c[ch[k] & 15]++;
        c[(ch[k] >> 4) & 15]++;
    }
#pragma unroll
    for (int e = 0; e < E_NUM; ++e) lcnt[e][tid] = c[e];
    __syncthreads();
    int wave = tid >> 6, lane = tid & 63;
    if (wave < E_NUM) {
        int base = 0;
        for (int chk = 0; chk < 16; ++chk) {
            int v = lcnt[wave][chk * 64 + lane];
            int inc = v;
#pragma unroll
            for (int d = 1; d < 64; d <<= 1) {
                int u = __shfl_up(inc, d, 64);
                if (lane >= d) inc += u;
            }
            lcnt[wave][chk * 64 + lane] = base + inc - v;  // exclusive prefix
            base += __shfl(inc, 63, 64);
        }
        if (lane == 0) tot[wave] = base;
    }
    __syncthreads();
    if (tid == 0) {
        int s = 0;
#pragma unroll
        for (int e = 0; e < E_NUM; ++e) { off[e] = s; cnt[e] = tot[e]; s += tot[e]; }
    }
    __syncthreads();
#pragma unroll
    for (int e = 0; e < E_NUM; ++e) c[e] = lcnt[e][tid];
#pragma unroll
    for (int k = 0; k < 8; ++k) {
        int t = tid * 8 + k;
        int i1 = ch[k] & 15, i2 = (ch[k] >> 4) & 15;
        float wA = twgt[t];
        int s1 = c[i1]++;
        int s2 = c[i2]++;
        tok_of[i1 * S_TOK + s1] = t; wgt_of[i1 * S_TOK + s1] = wA;
        tok_of[i2 * S_TOK + s2] = t; wgt_of[i2 * S_TOK + s2] = 1.0f - wA;
        slot_of[2 * t]     = ((unsigned)i1 << 20) | (unsigned)s1;
        slot_of[2 * t + 1] = ((unsigned)i2 << 20) | (unsigned)s2;
    }
}

// ---------------- combine: out[t] = pbuf[slotA] + pbuf[slotB] ----------------
__global__ void combine_kernel(const unsigned short* __restrict__ pbuf,
                               const unsigned int* __restrict__ slot_of,
                               const int* __restrict__ off, float* __restrict__ out) {
    int t = blockIdx.x, tid = threadIdx.x;
    unsigned int a = slot_of[2 * t], b = slot_of[2 * t + 1];
    size_t ra = (size_t)(off[a >> 20] + (int)(a & 0xFFFFFu));
    size_t rb = (size_t)(off[b >> 20] + (int)(b & 0xFFFFFu));
    const unsigned short* pa = pbuf + ra * H_DIM + tid * 8;
    const unsigned short* pb = pbuf + rb * H_DIM + tid * 8;
    ushort4 a0 = *(const ushort4*)pa, a1 = *(const ushort4*)(pa + 4);
    ushort4 b0 = *(const ushort4*)pb, b1 = *(const ushort4*)(pb + 4);
    float4 r0, r1;
    r0.x = bf2f(a0.x) + bf2f(b0.x); r0.y = bf2f(a0.y) + bf2f(b0.y);
    r0.z = bf2f(a0.z) + bf2f(b0.z); r0.w = bf2f(a0.w) + bf2f(b0.w);
    r1.x = bf2f(a1.x) + bf2f(b1.x); r1.y = bf2f(a1.y) + bf2f(b1.y);
    r1.z = bf2f(a1.z) + bf2f(b1.z); r1.w = bf2f(a1.w) + bf2f(b1.w);
    float* op = out + (size_t)t * H_DIM + tid * 8;
    *(float4*)op = r0;
    *(float4*)(op + 4) = r1;
}

// ---------------- 256x256 grouped GEMM, 32x32x16 MFMA, 2-phase schedule ----------------
// Per wave: output 128x64 = 4 mfrag(32 rows) x 2 nfrag(32 cols), acc[4][2] f32x16.
// K-tile 64 = 4 ksteps of 16. Per K-tile per wave: 24 ds_read_b128 (A 16 + B 8),
// 32 MFMA (half the instruction count of 16x16x32 at +15% pipe rate).
// Frag layouts (gfx950 family rule; C/D verified m74/m101):
//   A/B: lane l -> row/col l&31, k = (l>>5)*8 + j   (16B contiguous read)
//   C/D: col = l&31, row = (reg&3) + 8*(reg>>2) + 4*(l>>5)
// Iter T (cur=T&1):
//  P1: read all A(T)+B(T) (24 rds) | gB(0..3,T+1)->nxt | MFMA m0-1 | bar
//  P2: gA(0..3,T+2)->cur | MFMA m2-3 | vmcnt(4) | bar
// vmcnt(4) drains gA(T+1)x4 + gB(T+1)x4 leaving gA(T+2)x4 -> next iter's
// reads certified after the barrier (same proof as round 11).
template<int IS_G1>
__global__ __launch_bounds__(512, 2) void moe_gemm_kernel(
    const unsigned short* __restrict__ A_src, const unsigned short* __restrict__ W,
    const int* __restrict__ cnt, const int* __restrict__ off,
    const int* __restrict__ tok_of, const float* __restrict__ wgt_of,
    unsigned short* __restrict__ dst,
    const float* __restrict__ cvt_src, unsigned short* __restrict__ cvt_dst,
    long cvt_n, int gemm_grid, int cvt_blks, int nt_base, int cvt_mode) {
    if ((int)blockIdx.x >= gemm_grid) {
        long i0 = ((long)((int)blockIdx.x - gemm_grid) * blockDim.x + threadIdx.x) * 8;
        long stride = (long)cvt_blks * blockDim.x * 8;
        if (cvt_mode == 2) {
            cvt_w1_half_body<1>(cvt_src, cvt_dst, i0, stride);
        } else if (cvt_mode == 1) {
            for (long i = i0; i < cvt_n; i += stride) cvt8(cvt_src + i, cvt_dst + i);
        }
        return;
    }
    int bx = xcd_swizzle(blockIdx.x, gemm_grid);
    int nt = nt_base + bx / (E_NUM * 32);
    int rr = bx % (E_NUM * 32);
    int e = rr / 32;
    int mt = rr % 32;
    int C = cnt[e];
    if (mt * 256 >= C) return;
    int O = off[e];

    __shared__ __align__(16) char ldsA[2][32768];
    __shared__ __align__(16) char ldsB[2][32768];

    int tid = threadIdx.x;
    int wave = tid >> 6, lane = tid & 63;
    int wr = wave >> 2, wc = wave & 3;

    // ---- A staging source pointers (pre-swizzled involution) ----
    const char* aptr[4];
#pragma unroll
    for (int q = 0; q < 4; ++q) {
        int row = q * 64 + wave * 8 + (lane >> 3);
        int cu = (lane & 7) ^ (row & 7);
        int grow = mt * 256 + row; if (grow > C - 1) grow = C - 1;
        size_t arow = IS_G1 ? (size_t)tok_of[e * S_TOK + grow] : (size_t)(O + grow);
        aptr[q] = (const char*)(A_src + arow * 2048 + cu * 8);
    }
    // ---- B staging: identity LDS-row mapping ----
    // G1: lrow in [0,256): wcg=lrow>>6, n=(lrow>>5)&1 (0 gate,1 up), r=lrow&31
    //     -> w1 row = e*2I + n*I + nt*128 + wcg*32 + r
    // G2: w2 row = e*H + nt*256 + lrow
    const char* bptr[4];
#pragma unroll
    for (int j = 0; j < 4; ++j) {
        int lrow = j * 64 + wave * 8 + (lane >> 3);
        int cu = (lane & 7) ^ (lrow & 7);
        size_t brow;
        if (IS_G1) {
            int wcg = lrow >> 6, n = (lrow >> 5) & 1, r = lrow & 31;
            brow = (size_t)e * (2 * I_DIM) + (size_t)(n ? I_DIM : 0) +
                   (size_t)(nt * 128 + wcg * 32 + r);
        } else {
            brow = (size_t)e * H_DIM + nt * 256 + lrow;
        }
        bptr[j] = (const char*)(W + brow * 2048 + cu * 8);
    }

    // ---- swizzled ds_read byte offsets (32x32 frag pattern) ----
    // lane l: row = base + (l&31); 16B col unit cu = s*2 + (l>>5)
    int aoff[4][4], boff[2][4];
#pragma unroll
    for (int m = 0; m < 4; ++m)
#pragma unroll
        for (int s = 0; s < 4; ++s) {
            int row = wr * 128 + m * 32 + (lane & 31);
            int cu = s * 2 + (lane >> 5);
            aoff[m][s] = row * 128 + ((cu ^ (row & 7)) * 16);
        }
#pragma unroll
    for (int n = 0; n < 2; ++n)
#pragma unroll
        for (int s = 0; s < 4; ++s) {
            int lrow = wc * 64 + n * 32 + (lane & 31);
            int cu = s * 2 + (lane >> 5);
            boff[n][s] = lrow * 128 + ((cu ^ (lrow & 7)) * 16);
        }

    f32x16 acc[4][2];
#pragma unroll
    for (int m = 0; m < 4; ++m)
#pragma unroll
        for (int n = 0; n < 2; ++n)
#pragma unroll
            for (int q = 0; q < 16; ++q) acc[m][n][q] = 0.0f;

    auto gA = [&](int q, int T, int buf) {
        async_copy16(ldsA[buf] + q * 8192 + wave * 1024, aptr[q] + T * 128);
    };
    auto gB = [&](int j, int T, int buf) {
        async_copy16(ldsB[buf] + j * 8192 + wave * 1024, bptr[j] + T * 128);
    };

    // ---- prologue: A(0)->buf0, B(0)->buf0, A(1)->buf1 ----
    gA(0, 0, 0); gA(1, 0, 0); gA(2, 0, 0); gA(3, 0, 0);
    gB(0, 0, 0); gB(1, 0, 0); gB(2, 0, 0); gB(3, 0, 0);
    gA(0, 1, 1); gA(1, 1, 1); gA(2, 1, 1); gA(3, 1, 1);
    asm volatile("s_waitcnt vmcnt(4)" ::: "memory");  // A(0),B(0) landed
    __builtin_amdgcn_s_barrier();

    bf16x8 ar[4][4], br[2][4];
    int cur = 0;
#pragma unroll 2
    for (int T = 0; T < 32; ++T) {
        int nxt = cur ^ 1;
        int TA = (T + 2 < 32) ? T + 2 : 31;
        int TB = (T + 1 < 32) ? T + 1 : 31;
        // ---- P1: read all B + all A | gB(T+1)->nxt | MFMA m0-1 | bar ----
#pragma unroll
        for (int n = 0; n < 2; ++n)
#pragma unroll
            for (int s = 0; s < 4; ++s)
                br[n][s] = *(const bf16x8*)(ldsB[cur] + boff[n][s]);
#pragma unroll
        for (int m = 0; m < 4; ++m)
#pragma unroll
            for (int s = 0; s < 4; ++s)
                ar[m][s] = *(const bf16x8*)(ldsA[cur] + aoff[m][s]);
        gB(0, TB, nxt); gB(1, TB, nxt); gB(2, TB, nxt); gB(3, TB, nxt);
        __builtin_amdgcn_s_setprio(1);
#pragma unroll
        for (int m = 0; m < 2; ++m)
#pragma unroll
            for (int n = 0; n < 2; ++n)
#pragma unroll
                for (int s = 0; s < 4; ++s)
                    acc[m][n] = MFMA32(ar[m][s], br[n][s], acc[m][n]);
        __builtin_amdgcn_s_setprio(0);
        __builtin_amdgcn_s_barrier();
        // ---- P2: gA(T+2)->cur | MFMA m2-3 | vmcnt(4) | bar ----
        gA(0, TA, cur); gA(1, TA, cur); gA(2, TA, cur); gA(3, TA, cur);
        __builtin_amdgcn_s_setprio(1);
#pragma unroll
        for (int m = 2; m < 4; ++m)
#pragma unroll
            for (int n = 0; n < 2; ++n)
#pragma unroll
                for (int s = 0; s < 4; ++s)
                    acc[m][n] = MFMA32(ar[m][s], br[n][s], acc[m][n]);
        __builtin_amdgcn_s_setprio(0);
        asm volatile("s_waitcnt vmcnt(4)" ::: "memory");  // gA(T+1)+gB(T+1) landed
        __builtin_amdgcn_s_barrier();
        cur = nxt;
    }

    // ---- epilogue (C/D: col=lane&31, row=(reg&3)+8*(reg>>2)+4*(lane>>5)) ----
    int colj = lane & 31, rhi = (lane >> 5) * 4;
    if (IS_G1) {
#pragma unroll
        for (int m = 0; m < 4; ++m)
#pragma unroll
            for (int r = 0; r < 16; ++r) {
                int row = mt * 256 + wr * 128 + m * 32 + (r & 3) + 8 * (r >> 2) + rhi;
                if (row < C) {
                    float wgt = wgt_of[e * S_TOK + row];
                    float g = acc[m][0][r];
                    float u = acc[m][1][r];
                    float hv = (g / (1.0f + __expf(-g))) * u * wgt;
                    dst[(size_t)(O + row) * I_DIM + nt * 128 + wc * 32 + colj] = f2bf(hv);
                }
            }
    } else {
#pragma unroll
        for (int m = 0; m < 4; ++m)
#pragma unroll
            for (int r = 0; r < 16; ++r) {
                int row = mt * 256 + wr * 128 + m * 32 + (r & 3) + 8 * (r >> 2) + rhi;
                if (row < C) {
                    unsigned short* pp = dst + (size_t)(O + row) * H_DIM +
                                         nt * 256 + wc * 64 + colj;
                    pp[0] = f2bf(acc[m][0][r]);
                    pp[32] = f2bf(acc[m][1][r]);
                }
            }
    }
}

extern "C" void kernel_launch(void* const* d_in, const int* in_sizes, int n_in,
                              void* d_out, int out_size, void* d_ws, size_t ws_size,
                              hipStream_t stream) {
    const float* hs = (const float*)d_in[0];
    const float* wg = (const float*)d_in[1];
    const float* w1 = (const float*)d_in[2];
    const float* w2 = (const float*)d_in[3];

    float* out = (float*)d_out;
    float* logits = out + (size_t)S_TOK * H_DIM;

    char* ws = (char*)d_ws;
    int* cnt = (int*)ws;
    int* off = (int*)(ws + 256);
    int* tok_of = (int*)(ws + 512);
    float* wgt_of = (float*)(ws + 512 + (size_t)E_NUM * S_TOK * 4);
    unsigned int* slot_of = (unsigned int*)(ws + 512 + (size_t)E_NUM * S_TOK * 8);
    unsigned int* tchoice = (unsigned int*)(ws + 512 + (size_t)E_NUM * S_TOK * 8 + (size_t)S_TOK * 8);
    float* twgt = (float*)(ws + 512 + (size_t)E_NUM * S_TOK * 8 + (size_t)S_TOK * 12);
    size_t o = 512 + (size_t)E_NUM * S_TOK * 8 + (size_t)S_TOK * 16;
    o = (o + 4095) & ~(size_t)4095;
    unsigned short* hsb = (unsigned short*)(ws + o);  o += (size_t)S_TOK * H_DIM * 2;             // 32 MiB
    unsigned short* wxb = (unsigned short*)(ws + o);  o += (size_t)E_NUM * 2 * I_DIM * H_DIM * 2; // 128 MiB (w1)
    unsigned short* hbuf = (unsigned short*)(ws + o); o += (size_t)S_TOK * 2 * I_DIM * 2;         // 64 MiB
    size_t o_w2 = o;                                  // separate 64 MiB w2 region (fused mode)
    size_t need_fused = o_w2 + (size_t)E_NUM * H_DIM * I_DIM * 2;
    bool fused = (ws_size >= need_fused);

    const long W1_N = (long)E_NUM * 2 * I_DIM * H_DIM;
    const long W2_N = (long)E_NUM * H_DIM * I_DIM;
    const int GRID = E_NUM * 32 * 8;      // 2048 per GEMM launch
    const int CVT_BLKS = 1024;

    if (fused) {
        unsigned short* w2b = (unsigned short*)(ws + o_w2);
        unsigned short* pbuf = wxb;  // w1 dead after gemm1b
        // router + embedded cvt of w1-half0
        router_kernel<<<S_TOK + CVT_BLKS, 256, 0, stream>>>(
            hs, wg, logits, tchoice, twgt, hsb, w1, wxb, CVT_BLKS);
        scan_kernel<<<1, 1024, 0, stream>>>(tchoice, twgt, cnt, off, tok_of, wgt_of, slot_of);
        // gemm1a (nt 0-7) + trailing cvt blocks: w1-half1
        moe_gemm_kernel<1><<<GRID + CVT_BLKS, 512, 0, stream>>>(
            hsb, wxb, cnt, off, tok_of, wgt_of, hbuf,
            w1, wxb, 0, GRID, CVT_BLKS, 0, 2);
        // gemm1b (nt 8-15) + trailing cvt blocks: w2
        moe_gemm_kernel<1><<<GRID + CVT_BLKS, 512, 0, stream>>>(
            hsb, wxb, cnt, off, tok_of, wgt_of, hbuf,
            w2, w2b, W2_N, GRID, CVT_BLKS, 8, 1);
        moe_gemm_kernel<0><<<GRID, 512, 0, stream>>>(
            hbuf, w2b, cnt, off, tok_of, wgt_of, pbuf,
            nullptr, nullptr, 0, GRID, 0, 0, 0);
        combine_kernel<<<S_TOK, 256, 0, stream>>>(pbuf, slot_of, off, out);
    } else {
        unsigned short* w2b = wxb;
        unsigned short* pbuf = wxb + (size_t)E_NUM * H_DIM * I_DIM;
        router_kernel<<<S_TOK, 256, 0, stream>>>(
            hs, wg, logits, tchoice, twgt, hsb, nullptr, nullptr, 1);
        scan_kernel<<<1, 1024, 0, stream>>>(tchoice, twgt, cnt, off, tok_of, wgt_of, slot_of);
        cvt_kernel<<<4096, 256, 0, stream>>>(w1, wxb, W1_N);
        moe_gemm_kernel<1><<<GRID, 512, 0, stream>>>(
            hsb, wxb, cnt, off, tok_of, wgt_of, hbuf, nullptr, nullptr, 0, GRID, 0, 0, 0);
        moe_gemm_kernel<1><<<GRID, 512, 0, stream>>>(
            hsb, wxb, cnt, off, tok_of, wgt_of, hbuf, nullptr, nullptr, 0, GRID, 0, 8, 0);
        cvt_kernel<<<4096, 256, 0, stream>>>(w2, w2b, W2_N);
        moe_gemm_kernel<0><<<GRID, 512, 0, stream>>>(
            hbuf, w2b, cnt, off, tok_of, wgt_of, pbuf, nullptr, nullptr, 0, GRID, 0, 0, 0);
        combine_kernel<<<S_TOK, 256, 0, stream>>>(pbuf, slot_of, off, out);
    }
}

// Round 13
// 604.538 us; speedup vs baseline: 1.3931x; 1.3931x over previous
//
#include <hip/hip_runtime.h>
#include <hip/hip_bf16.h>
#include <stdint.h>

#define S_TOK 8192
#define H_DIM 2048
#define I_DIM 2048
#define E_NUM 8

typedef __attribute__((ext_vector_type(4))) float f32x4;
typedef __attribute__((ext_vector_type(8))) short bf16x8;
typedef __attribute__((ext_vector_type(8))) unsigned short u16x8;

#define MFMA16(a, b, c) __builtin_amdgcn_mfma_f32_16x16x32_bf16((a), (b), (c), 0, 0, 0)

// f32 -> bf16 RNE
__device__ __forceinline__ unsigned short f2bf(float f) {
    unsigned int u = __float_as_uint(f);
    unsigned int r = (u + 0x7FFFu + ((u >> 16) & 1u)) >> 16;
    return (unsigned short)r;
}
__device__ __forceinline__ float bf2f(unsigned short u) {
    return __uint_as_float((unsigned int)u << 16);
}

__device__ __forceinline__ void cvt8(const float* __restrict__ s, unsigned short* __restrict__ d) {
    float4 v0 = *(const float4*)s;
    float4 v1 = *(const float4*)(s + 4);
    u16x8 o;
    o[0] = f2bf(v0.x); o[1] = f2bf(v0.y); o[2] = f2bf(v0.z); o[3] = f2bf(v0.w);
    o[4] = f2bf(v1.x); o[5] = f2bf(v1.y); o[6] = f2bf(v1.z); o[7] = f2bf(v1.w);
    *(u16x8*)d = o;
}

// async global->LDS, 16B per lane. LDS dest is wave-uniform base + lane*16.
__device__ __forceinline__ void async_copy16(void* lds, const void* g) {
    __builtin_amdgcn_global_load_lds(
        (const __attribute__((address_space(1))) void*)(uintptr_t)g,
        (__attribute__((address_space(3))) void*)(uintptr_t)lds,
        16, 0, 0);
}

// XCD-aware block swizzle (nwg % 8 == 0 for all our grids)
__device__ __forceinline__ int xcd_swizzle(int bid, int nwg) {
    int cpx = nwg >> 3;
    return (bid & 7) * cpx + (bid >> 3);
}

// ---------------- flat f32 -> bf16 conversion (fallback path) ----------------
__global__ void cvt_kernel(const float* __restrict__ src, unsigned short* __restrict__ dst, long n) {
    long i0 = ((long)blockIdx.x * blockDim.x + threadIdx.x) * 8;
    long stride = (long)gridDim.x * blockDim.x * 8;
    for (long i = i0; i < n; i += stride) cvt8(src + i, dst + i);
}

// ---------------- w1 half conversion ----------------
// HALF=0: gate rows [0,1024) + up rows [0,1024) per expert (needed by nt<8).
// HALF=1: gate/up rows [1024,2048) (needed by nt>=8).
template<int HALF>
__device__ __forceinline__ void cvt_w1_half_body(const float* __restrict__ src,
                                                 unsigned short* __restrict__ dst,
                                                 long i0, long stride) {
    const long CH = 1L << 21;                 // 1024*2048
    const long TOT = (long)E_NUM * 2 * CH;    // 16.8M
    for (long j = i0; j < TOT; j += stride) {
        long e = j >> 22;
        long piece = (j >> 21) & 1;
        long off = j & (CH - 1);
        long g = (e << 23) + ((piece * 2 + HALF) << 21) + off;
        cvt8(src + g, dst + g);
    }
}

// ---------------- router: logits (f32 exact), top-2 choice, hs->bf16 ----------------
// Extra blocks (bid >= S_TOK) convert w1-half0.
__global__ void router_kernel(const float* __restrict__ hs, const float* __restrict__ wg,
                              float* __restrict__ logits,
                              unsigned int* __restrict__ tchoice, float* __restrict__ twgt,
                              unsigned short* __restrict__ hsb,
                              const float* __restrict__ w1src, unsigned short* __restrict__ w1dst,
                              int cvt_blks) {
    if ((int)blockIdx.x >= S_TOK) {
        long i0 = ((long)((int)blockIdx.x - S_TOK) * blockDim.x + threadIdx.x) * 8;
        long stride = (long)cvt_blks * blockDim.x * 8;
        cvt_w1_half_body<0>(w1src, w1dst, i0, stride);
        return;
    }
    int t = blockIdx.x;
    int tid = threadIdx.x;
    const float* hrow = hs + (size_t)t * H_DIM;
    float4 h0 = *(const float4*)(hrow + tid * 8);
    float4 h1 = *(const float4*)(hrow + tid * 8 + 4);
    u16x8 o;
    o[0] = f2bf(h0.x); o[1] = f2bf(h0.y); o[2] = f2bf(h0.z); o[3] = f2bf(h0.w);
    o[4] = f2bf(h1.x); o[5] = f2bf(h1.y); o[6] = f2bf(h1.z); o[7] = f2bf(h1.w);
    *(u16x8*)(hsb + (size_t)t * H_DIM + tid * 8) = o;

    float p[E_NUM];
#pragma unroll
    for (int e = 0; e < E_NUM; ++e) {
        const float* w = wg + (size_t)e * H_DIM + tid * 8;
        float4 w0 = *(const float4*)(w);
        float4 w1v = *(const float4*)(w + 4);
        p[e] = h0.x * w0.x + h0.y * w0.y + h0.z * w0.z + h0.w * w0.w +
               h1.x * w1v.x + h1.y * w1v.y + h1.z * w1v.z + h1.w * w1v.w;
    }
#pragma unroll
    for (int e = 0; e < E_NUM; ++e)
#pragma unroll
        for (int d = 32; d > 0; d >>= 1) p[e] += __shfl_xor(p[e], d, 64);

    __shared__ float red[4][E_NUM];
    int wave = tid >> 6, lane = tid & 63;
    if (lane == 0) {
#pragma unroll
        for (int e = 0; e < E_NUM; ++e) red[wave][e] = p[e];
    }
    __syncthreads();
    if (tid == 0) {
        float l[E_NUM];
#pragma unroll
        for (int e = 0; e < E_NUM; ++e) l[e] = red[0][e] + red[1][e] + red[2][e] + red[3][e];
#pragma unroll
        for (int e = 0; e < E_NUM; ++e) logits[(size_t)t * E_NUM + e] = l[e];
        int i1 = 0;
#pragma unroll
        for (int e = 1; e < E_NUM; ++e) if (l[e] > l[i1]) i1 = e;
        int i2 = (i1 == 0) ? 1 : 0;
#pragma unroll
        for (int e = 0; e < E_NUM; ++e) if (e != i1 && l[e] > l[i2]) i2 = e;
        float b = __expf(l[i2] - l[i1]);
        tchoice[t] = (unsigned)i1 | ((unsigned)i2 << 4);
        twgt[t] = 1.0f / (1.0f + b);
    }
}

// ---------------- scan: deterministic slot assignment (token order) ----------------
__global__ __launch_bounds__(1024) void scan_kernel(
    const unsigned int* __restrict__ tchoice, const float* __restrict__ twgt,
    int* __restrict__ cnt, int* __restrict__ off,
    int* __restrict__ tok_of, float* __restrict__ wgt_of,
    unsigned int* __restrict__ slot_of) {
    __shared__ int lcnt[E_NUM][1024];
    __shared__ int tot[E_NUM];
    int tid = threadIdx.x;
    unsigned int ch[8];
    int c[E_NUM];
#pragma unroll
    for (int e = 0; e < E_NUM; ++e) c[e] = 0;
#pragma unroll
    for (int k = 0; k < 8; ++k) {
        ch[k] = tchoice[tid * 8 + k];
        c[ch[k] & 15]++;
        c[(ch[k] >> 4) & 15]++;
    }
#pragma unroll
    for (int e = 0; e < E_NUM; ++e) lcnt[e][tid] = c[e];
    __syncthreads();
    int wave = tid >> 6, lane = tid & 63;
    if (wave < E_NUM) {
        int base = 0;
        for (int chk = 0; chk < 16; ++chk) {
            int v = lcnt[wave][chk * 64 + lane];
            int inc = v;
#pragma unroll
            for (int d = 1; d < 64; d <<= 1) {
                int u = __shfl_up(inc, d, 64);
                if (lane >= d) inc += u;
            }
            lcnt[wave][chk * 64 + lane] = base + inc - v;  // exclusive prefix
            base += __shfl(inc, 63, 64);
        }
        if (lane == 0) tot[wave] = base;
    }
    __syncthreads();
    if (tid == 0) {
        int s = 0;
#pragma unroll
        for (int e = 0; e < E_NUM; ++e) { off[e] = s; cnt[e] = tot[e]; s += tot[e]; }
    }
    __syncthreads();
#pragma unroll
    for (int e = 0; e < E_NUM; ++e) c[e] = lcnt[e][tid];
#pragma unroll
    for (int k = 0; k < 8; ++k) {
        int t = tid * 8 + k;
        int i1 = ch[k] & 15, i2 = (ch[k] >> 4) & 15;
        float wA = twgt[t];
        int s1 = c[i1]++;
        int s2 = c[i2]++;
        tok_of[i1 * S_TOK + s1] = t; wgt_of[i1 * S_TOK + s1] = wA;
        tok_of[i2 * S_TOK + s2] = t; wgt_of[i2 * S_TOK + s2] = 1.0f - wA;
        slot_of[2 * t]     = ((unsigned)i1 << 20) | (unsigned)s1;
        slot_of[2 * t + 1] = ((unsigned)i2 << 20) | (unsigned)s2;
    }
}

// ---------------- combine: out[t] = pbuf[slotA] + pbuf[slotB] ----------------
__global__ void combine_kernel(const unsigned short* __restrict__ pbuf,
                               const unsigned int* __restrict__ slot_of,
                               const int* __restrict__ off, float* __restrict__ out) {
    int t = blockIdx.x, tid = threadIdx.x;
    unsigned int a = slot_of[2 * t], b = slot_of[2 * t + 1];
    size_t ra = (size_t)(off[a >> 20] + (int)(a & 0xFFFFFu));
    size_t rb = (size_t)(off[b >> 20] + (int)(b & 0xFFFFFu));
    const unsigned short* pa = pbuf + ra * H_DIM + tid * 8;
    const unsigned short* pb = pbuf + rb * H_DIM + tid * 8;
    ushort4 a0 = *(const ushort4*)pa, a1 = *(const ushort4*)(pa + 4);
    ushort4 b0 = *(const ushort4*)pb, b1 = *(const ushort4*)(pb + 4);
    float4 r0, r1;
    r0.x = bf2f(a0.x) + bf2f(b0.x); r0.y = bf2f(a0.y) + bf2f(b0.y);
    r0.z = bf2f(a0.z) + bf2f(b0.z); r0.w = bf2f(a0.w) + bf2f(b0.w);
    r1.x = bf2f(a1.x) + bf2f(b1.x); r1.y = bf2f(a1.y) + bf2f(b1.y);
    r1.z = bf2f(a1.z) + bf2f(b1.z); r1.w = bf2f(a1.w) + bf2f(b1.w);
    float* op = out + (size_t)t * H_DIM + tid * 8;
    *(float4*)op = r0;
    *(float4*)(op + 4) = r1;
}

// ---------------- 8-phase 256x256 grouped GEMM (round-7 structure, best measured) ----------------
// Phase = {ds_read | stage-issue | setprio(1) MFMA setprio(0) | [vmcnt] | bar}.
// 16x16x32 MFMA, XOR-swizzled LDS (0 bank conflicts), counted vmcnt queue:
//   P1: rd B.np0 + A.m0-3 | gB h0(T+1) | mfma m0-3 x n0-1 | bar
//   P2: rd A.m4-7 | gA q0,q2(T+2) | mfma m4-7 x n0-1 | vmcnt(4) bar
//   P3: rd B.np1 | gA q1,q3(T+2) | mfma m0-3 x n2-3 | bar
//   P4: gB h1(T+1) | mfma m4-7 x n2-3 | vmcnt(6) bar
// Blocks with bid >= gemm_grid run an embedded cvt loop; null GEMM blocks
// (mt beyond expert count) exit immediately.
template<int IS_G1>
__global__ __launch_bounds__(512, 2) void moe_gemm_kernel(
    const unsigned short* __restrict__ A_src, const unsigned short* __restrict__ W,
    const int* __restrict__ cnt, const int* __restrict__ off,
    const int* __restrict__ tok_of, const float* __restrict__ wgt_of,
    unsigned short* __restrict__ dst,
    const float* __restrict__ cvt_src, unsigned short* __restrict__ cvt_dst,
    long cvt_n, int gemm_grid, int cvt_blks, int nt_base, int cvt_mode) {
    if ((int)blockIdx.x >= gemm_grid) {
        long i0 = ((long)((int)blockIdx.x - gemm_grid) * blockDim.x + threadIdx.x) * 8;
        long stride = (long)cvt_blks * blockDim.x * 8;
        if (cvt_mode == 2) {
            cvt_w1_half_body<1>(cvt_src, cvt_dst, i0, stride);
        } else if (cvt_mode == 1) {
            for (long i = i0; i < cvt_n; i += stride) cvt8(cvt_src + i, cvt_dst + i);
        }
        return;
    }
    int bx = xcd_swizzle(blockIdx.x, gemm_grid);
    int nt = nt_base + bx / (E_NUM * 32);
    int rr = bx % (E_NUM * 32);
    int e = rr / 32;
    int mt = rr % 32;
    int C = cnt[e];
    if (mt * 256 >= C) return;
    int O = off[e];

    __shared__ __align__(16) char ldsA[2][32768];
    __shared__ __align__(16) char ldsB[2][32768];

    int tid = threadIdx.x;
    int wave = tid >> 6, lane = tid & 63;
    int wr = wave >> 2, wc = wave & 3;

    // ---- staging source pointers (pre-swizzled involution) ----
    const char* aptr[4];
#pragma unroll
    for (int q = 0; q < 4; ++q) {
        int row = q * 64 + wave * 8 + (lane >> 3);
        int cu = (lane & 7) ^ (row & 7);
        int grow = mt * 256 + row; if (grow > C - 1) grow = C - 1;
        size_t arow = IS_G1 ? (size_t)tok_of[e * S_TOK + grow] : (size_t)(O + grow);
        aptr[q] = (const char*)(A_src + arow * 2048 + cu * 8);
    }
    const char* bptr[4];
#pragma unroll
    for (int j = 0; j < 4; ++j) {
        int lrow = j * 64 + wave * 8 + (lane >> 3);
        int cu = (lane & 7) ^ (lrow & 7);
        int np = lrow >> 7, wcg = (lrow >> 5) & 3, rem = lrow & 31;
        int tbrow = wcg * 64 + np * 32 + rem;
        size_t brow;
        if (IS_G1) {
            int jj = tbrow & 63, wq = tbrow >> 6;
            if (jj < 32) brow = (size_t)(nt * 128 + wq * 32 + jj);
            else         brow = (size_t)I_DIM + nt * 128 + wq * 32 + (jj - 32);
            brow += (size_t)e * (2 * I_DIM);
        } else {
            brow = (size_t)e * H_DIM + nt * 256 + tbrow;
        }
        bptr[j] = (const char*)(W + brow * 2048 + cu * 8);
    }

    // ---- swizzled ds_read byte offsets ----
    int aoff[8][2], boff[4][2];
#pragma unroll
    for (int m = 0; m < 8; ++m)
#pragma unroll
        for (int ks = 0; ks < 2; ++ks) {
            int row = wr * 128 + m * 16 + (lane & 15);
            int cu = ks * 4 + (lane >> 4);
            aoff[m][ks] = row * 128 + ((cu ^ (row & 7)) * 16);
        }
#pragma unroll
    for (int n = 0; n < 4; ++n)
#pragma unroll
        for (int ks = 0; ks < 2; ++ks) {
            int lrow = (n >> 1) * 128 + wc * 32 + (n & 1) * 16 + (lane & 15);
            int cu = ks * 4 + (lane >> 4);
            boff[n][ks] = lrow * 128 + ((cu ^ (lrow & 7)) * 16);
        }

    f32x4 acc[8][4];
#pragma unroll
    for (int m = 0; m < 8; ++m)
#pragma unroll
        for (int n = 0; n < 4; ++n)
#pragma unroll
            for (int q = 0; q < 4; ++q) acc[m][n][q] = 0.0f;

    auto gA = [&](int q, int T, int buf) {
        async_copy16(ldsA[buf] + q * 8192 + wave * 1024, aptr[q] + T * 128);
    };
    auto gB = [&](int j, int T, int buf) {
        async_copy16(ldsB[buf] + j * 8192 + wave * 1024, bptr[j] + T * 128);
    };

    // ---- prologue: A0(q0,q2,q1,q3) B0h0 A1(all) B0h1 ----
    gA(0, 0, 0); gA(2, 0, 0); gA(1, 0, 0); gA(3, 0, 0);
    gB(0, 0, 0); gB(1, 0, 0);
    gA(0, 1, 1); gA(2, 1, 1); gA(1, 1, 1); gA(3, 1, 1);
    gB(2, 0, 0); gB(3, 0, 0);
    asm volatile("s_waitcnt vmcnt(6)" ::: "memory");
    __builtin_amdgcn_s_barrier();

    bf16x8 ar[8][2], br[2][2];
    int cur = 0;
#pragma unroll 2
    for (int T = 0; T < 32; ++T) {
        int nxt = cur ^ 1;
        int TA = (T + 2 < 32) ? T + 2 : 31;
        int TB = (T + 1 < 32) ? T + 1 : 31;
        // ---- P1 ----
#pragma unroll
        for (int n = 0; n < 2; ++n)
#pragma unroll
            for (int ks = 0; ks < 2; ++ks)
                br[n][ks] = *(const bf16x8*)(ldsB[cur] + boff[n][ks]);
#pragma unroll
        for (int m = 0; m < 4; ++m)
#pragma unroll
            for (int ks = 0; ks < 2; ++ks)
                ar[m][ks] = *(const bf16x8*)(ldsA[cur] + aoff[m][ks]);
        gB(0, TB, nxt); gB(1, TB, nxt);
        __builtin_amdgcn_s_setprio(1);
#pragma unroll
        for (int m = 0; m < 4; ++m)
#pragma unroll
            for (int n = 0; n < 2; ++n) {
                acc[m][n] = MFMA16(ar[m][0], br[n][0], acc[m][n]);
                acc[m][n] = MFMA16(ar[m][1], br[n][1], acc[m][n]);
            }
        __builtin_amdgcn_s_setprio(0);
        __builtin_amdgcn_s_barrier();
        // ---- P2 ----
#pragma unroll
        for (int m = 4; m < 8; ++m)
#pragma unroll
            for (int ks = 0; ks < 2; ++ks)
                ar[m][ks] = *(const bf16x8*)(ldsA[cur] + aoff[m][ks]);
        gA(0, TA, cur); gA(2, TA, cur);
        __builtin_amdgcn_s_setprio(1);
#pragma unroll
        for (int m = 4; m < 8; ++m)
#pragma unroll
            for (int n = 0; n < 2; ++n) {
                acc[m][n] = MFMA16(ar[m][0], br[n][0], acc[m][n]);
                acc[m][n] = MFMA16(ar[m][1], br[n][1], acc[m][n]);
            }
        __builtin_amdgcn_s_setprio(0);
        asm volatile("s_waitcnt vmcnt(4)" ::: "memory");
        __builtin_amdgcn_s_barrier();
        // ---- P3 ----
#pragma unroll
        for (int n = 0; n < 2; ++n)
#pragma unroll
            for (int ks = 0; ks < 2; ++ks)
                br[n][ks] = *(const bf16x8*)(ldsB[cur] + boff[n + 2][ks]);
        gA(1, TA, cur); gA(3, TA, cur);
        __builtin_amdgcn_s_setprio(1);
#pragma unroll
        for (int m = 0; m < 4; ++m)
#pragma unroll
            for (int n = 0; n < 2; ++n) {
                acc[m][n + 2] = MFMA16(ar[m][0], br[n][0], acc[m][n + 2]);
                acc[m][n + 2] = MFMA16(ar[m][1], br[n][1], acc[m][n + 2]);
            }
        __builtin_amdgcn_s_setprio(0);
        __builtin_amdgcn_s_barrier();
        // ---- P4 ----
        gB(2, TB, nxt); gB(3, TB, nxt);
        __builtin_amdgcn_s_setprio(1);
#pragma unroll
        for (int m = 4; m < 8; ++m)
#pragma unroll
            for (int n = 0; n < 2; ++n) {
                acc[m][n + 2] = MFMA16(ar[m][0], br[n][0], acc[m][n + 2]);
                acc[m][n + 2] = MFMA16(ar[m][1], br[n][1], acc[m][n + 2]);
            }
        __builtin_amdgcn_s_setprio(0);
        asm volatile("s_waitcnt vmcnt(6)" ::: "memory");
        __builtin_amdgcn_s_barrier();
        cur = nxt;
    }

    // ---- epilogue ----
    if (IS_G1) {
#pragma unroll
        for (int m = 0; m < 8; ++m)
#pragma unroll
            for (int q = 0; q < 4; ++q) {
                int row = mt * 256 + wr * 128 + m * 16 + (lane >> 4) * 4 + q;
                if (row < C) {
                    float wgt = wgt_of[e * S_TOK + row];
                    unsigned short* hp = dst + (size_t)(O + row) * I_DIM +
                                         nt * 128 + wc * 32 + (lane & 15);
#pragma unroll
                    for (int n = 0; n < 2; ++n) {
                        float g = acc[m][n][q];
                        float u = acc[m][n + 2][q];
                        float hv = (g / (1.0f + __expf(-g))) * u * wgt;
                        hp[n * 16] = f2bf(hv);
                    }
                }
            }
    } else {
#pragma unroll
        for (int m = 0; m < 8; ++m)
#pragma unroll
            for (int q = 0; q < 4; ++q) {
                int row = mt * 256 + wr * 128 + m * 16 + (lane >> 4) * 4 + q;
                if (row < C) {
                    unsigned short* pp = dst + (size_t)(O + row) * H_DIM +
                                         nt * 256 + wc * 64 + (lane & 15);
#pragma unroll
                    for (int n = 0; n < 4; ++n)
                        pp[n * 16] = f2bf(acc[m][n][q]);
                }
            }
    }
}

extern "C" void kernel_launch(void* const* d_in, const int* in_sizes, int n_in,
                              void* d_out, int out_size, void* d_ws, size_t ws_size,
                              hipStream_t stream) {
    const float* hs = (const float*)d_in[0];
    const float* wg = (const float*)d_in[1];
    const float* w1 = (const float*)d_in[2];
    const float* w2 = (const float*)d_in[3];

    float* out = (float*)d_out;
    float* logits = out + (size_t)S_TOK * H_DIM;

    char* ws = (char*)d_ws;
    int* cnt = (int*)ws;
    int* off = (int*)(ws + 256);
    int* tok_of = (int*)(ws + 512);
    float* wgt_of = (float*)(ws + 512 + (size_t)E_NUM * S_TOK * 4);
    unsigned int* slot_of = (unsigned int*)(ws + 512 + (size_t)E_NUM * S_TOK * 8);
    unsigned int* tchoice = (unsigned int*)(ws + 512 + (size_t)E_NUM * S_TOK * 8 + (size_t)S_TOK * 8);
    float* twgt = (float*)(ws + 512 + (size_t)E_NUM * S_TOK * 8 + (size_t)S_TOK * 12);
    size_t o = 512 + (size_t)E_NUM * S_TOK * 8 + (size_t)S_TOK * 16;
    o = (o + 4095) & ~(size_t)4095;
    unsigned short* hsb = (unsigned short*)(ws + o);  o += (size_t)S_TOK * H_DIM * 2;             // 32 MiB
    unsigned short* wxb = (unsigned short*)(ws + o);  o += (size_t)E_NUM * 2 * I_DIM * H_DIM * 2; // 128 MiB (w1)
    unsigned short* hbuf = (unsigned short*)(ws + o); o += (size_t)S_TOK * 2 * I_DIM * 2;         // 64 MiB
    size_t o_w2 = o;                                  // separate 64 MiB w2 region (fused mode)
    size_t need_fused = o_w2 + (size_t)E_NUM * H_DIM * I_DIM * 2;
    bool fused = (ws_size >= need_fused);

    const long W1_N = (long)E_NUM * 2 * I_DIM * H_DIM;
    const long W2_N = (long)E_NUM * H_DIM * I_DIM;
    const int GRID = E_NUM * 32 * 8;      // 2048 per GEMM launch
    const int CVT_BLKS = 1024;

    if (fused) {
        unsigned short* w2b = (unsigned short*)(ws + o_w2);
        unsigned short* pbuf = wxb;  // w1 dead after gemm1b
        // router + embedded cvt of w1-half0
        router_kernel<<<S_TOK + CVT_BLKS, 256, 0, stream>>>(
            hs, wg, logits, tchoice, twgt, hsb, w1, wxb, CVT_BLKS);
        scan_kernel<<<1, 1024, 0, stream>>>(tchoice, twgt, cnt, off, tok_of, wgt_of, slot_of);
        // gemm1a (nt 0-7) + trailing cvt blocks: w1-half1
        moe_gemm_kernel<1><<<GRID + CVT_BLKS, 512, 0, stream>>>(
            hsb, wxb, cnt, off, tok_of, wgt_of, hbuf,
            w1, wxb, 0, GRID, CVT_BLKS, 0, 2);
        // gemm1b (nt 8-15) + trailing cvt blocks: w2
        moe_gemm_kernel<1><<<GRID + CVT_BLKS, 512, 0, stream>>>(
            hsb, wxb, cnt, off, tok_of, wgt_of, hbuf,
            w2, w2b, W2_N, GRID, CVT_BLKS, 8, 1);
        moe_gemm_kernel<0><<<GRID, 512, 0, stream>>>(
            hbuf, w2b, cnt, off, tok_of, wgt_of, pbuf,
            nullptr, nullptr, 0, GRID, 0, 0, 0);
        combine_kernel<<<S_TOK, 256, 0, stream>>>(pbuf, slot_of, off, out);
    } else {
        unsigned short* w2b = wxb;
        unsigned short* pbuf = wxb + (size_t)E_NUM * H_DIM * I_DIM;
        router_kernel<<<S_TOK, 256, 0, stream>>>(
            hs, wg, logits, tchoice, twgt, hsb, nullptr, nullptr, 1);
        scan_kernel<<<1, 1024, 0, stream>>>(tchoice, twgt, cnt, off, tok_of, wgt_of, slot_of);
        cvt_kernel<<<4096, 256, 0, stream>>>(w1, wxb, W1_N);
        moe_gemm_kernel<1><<<GRID, 512, 0, stream>>>(
            hsb, wxb, cnt, off, tok_of, wgt_of, hbuf, nullptr, nullptr, 0, GRID, 0, 0, 0);
        moe_gemm_kernel<1><<<GRID, 512, 0, stream>>>(
            hsb, wxb, cnt, off, tok_of, wgt_of, hbuf, nullptr, nullptr, 0, GRID, 0, 8, 0);
        cvt_kernel<<<4096, 256, 0, stream>>>(w2, w2b, W2_N);
        moe_gemm_kernel<0><<<GRID, 512, 0, stream>>>(
            hbuf, w2b, cnt, off, tok_of, wgt_of, pbuf, nullptr, nullptr, 0, GRID, 0, 0, 0);
        combine_kernel<<<S_TOK, 256, 0, stream>>>(pbuf, slot_of, off, out);
    }
}